// Round 9
// baseline (280.002 us; speedup 1.0000x reference)
//
#include <hip/hip_runtime.h>

#define EMBED 1024
#define THREE_EMBED 3072
#define HEADS 16
#define HDIM 64
#define SEQ 2048
#define BATCH 2
#define MTOT 4096  // B*T

typedef short bf16x8 __attribute__((ext_vector_type(8)));
typedef float f32x4 __attribute__((ext_vector_type(4)));

#define MFMA16(a, b, c) __builtin_amdgcn_mfma_f32_16x16x32_bf16(a, b, c, 0, 0, 0)

__device__ __forceinline__ unsigned short f2bf(float f) {
  union { float f; unsigned int u; } v; v.f = f;
  unsigned int r = v.u + 0x7fffu + ((v.u >> 16) & 1u);
  return (unsigned short)(r >> 16);
}

// async 16B global->LDS. LDS dest is wave-uniform base + lane*16 (HW semantics).
__device__ __forceinline__ void gload_lds16(const unsigned short* g, unsigned short* l) {
  __builtin_amdgcn_global_load_lds(
      (const __attribute__((address_space(1))) void*)g,
      (__attribute__((address_space(3))) void*)l, 16, 0, 0);
}

__device__ __forceinline__ void wait_vm0_barrier() {
  asm volatile("s_waitcnt vmcnt(0)" ::: "memory");
  __builtin_amdgcn_s_barrier();
}

template <int N>
__device__ __forceinline__ void wait_vmcnt() {
  if constexpr (N == 0) asm volatile("s_waitcnt vmcnt(0)" ::: "memory");
  else if constexpr (N == 1) asm volatile("s_waitcnt vmcnt(1)" ::: "memory");
  else if constexpr (N == 2) asm volatile("s_waitcnt vmcnt(2)" ::: "memory");
  else if constexpr (N == 3) asm volatile("s_waitcnt vmcnt(3)" ::: "memory");
  else if constexpr (N == 4) asm volatile("s_waitcnt vmcnt(4)" ::: "memory");
  else if constexpr (N == 6) asm volatile("s_waitcnt vmcnt(6)" ::: "memory");
  else if constexpr (N == 8) asm volatile("s_waitcnt vmcnt(8)" ::: "memory");
}

// ---------------- transpose fp32 [K][N] -> bf16 [N][K] ----------------
__global__ __launch_bounds__(256) void k_transpose_bf16(
    const float* __restrict__ in, unsigned short* __restrict__ out, int K, int N) {
  __shared__ float t[32][33];
  int tx = threadIdx.x & 31, ty = threadIdx.x >> 5;
  int n0 = blockIdx.x * 32, k0 = blockIdx.y * 32;
#pragma unroll
  for (int i = 0; i < 32; i += 8)
    t[ty + i][tx] = in[(size_t)(k0 + ty + i) * N + n0 + tx];
  __syncthreads();
#pragma unroll
  for (int i = 0; i < 32; i += 8)
    out[(size_t)(n0 + ty + i) * K + k0 + tx] = f2bf(t[tx][ty + i]);
}

// ---------------- V transpose: qkv V-part -> Vt[bh][64][2048] bf16 ----------------
__global__ __launch_bounds__(256) void k_transpose_v(
    const unsigned short* __restrict__ qkv, unsigned short* __restrict__ Vt) {
  __shared__ unsigned short t[32][33];
  int tx = threadIdx.x & 31, ty = threadIdx.x >> 5;  // 32 x 8
  int t0 = blockIdx.x * 32;
  int d0 = (blockIdx.y & 1) * 32;
  int bh = blockIdx.y >> 1;
  int b = bh >> 4, h = bh & 15;
  const unsigned short* src = qkv + (size_t)b * SEQ * THREE_EMBED + 2 * EMBED + h * HDIM;
#pragma unroll
  for (int i = 0; i < 32; i += 8)
    t[ty + i][tx] = src[(size_t)(t0 + ty + i) * THREE_EMBED + d0 + tx];
  __syncthreads();
  unsigned short* dst = Vt + (size_t)bh * HDIM * SEQ;
#pragma unroll
  for (int i = 0; i < 32; i += 8)
    dst[(size_t)(d0 + ty + i) * SEQ + t0 + tx] = t[tx][ty + i];
}

// ---------------- layernorm fp32 [4096][1024] -> bf16 ----------------
__global__ __launch_bounds__(256) void k_layernorm(
    const float* __restrict__ x, const float* __restrict__ g,
    const float* __restrict__ b, unsigned short* __restrict__ out) {
  int row = blockIdx.x;
  int tid = threadIdx.x;
  const float4 xv = *(const float4*)(x + (size_t)row * EMBED + tid * 4);
  float s = xv.x + xv.y + xv.z + xv.w;
  float sq = xv.x * xv.x + xv.y * xv.y + xv.z * xv.z + xv.w * xv.w;
#pragma unroll
  for (int off = 1; off < 64; off <<= 1) {
    s += __shfl_xor(s, off);
    sq += __shfl_xor(sq, off);
  }
  __shared__ float red[8];
  int w = tid >> 6;
  if ((tid & 63) == 0) { red[w] = s; red[4 + w] = sq; }
  __syncthreads();
  s = red[0] + red[1] + red[2] + red[3];
  sq = red[4] + red[5] + red[6] + red[7];
  float mu = s * (1.0f / EMBED);
  float var = sq * (1.0f / EMBED) - mu * mu;
  float rs = rsqrtf(var + 1e-5f);
  float xs[4] = {xv.x, xv.y, xv.z, xv.w};
  unsigned short o[4];
#pragma unroll
  for (int c = 0; c < 4; c++) {
    int col = tid * 4 + c;
    o[c] = f2bf((xs[c] - mu) * rs * g[col] + b[col]);
  }
  *(ushort4*)(out + (size_t)row * EMBED + tid * 4) = *(const ushort4*)o;
}

// ---- bf16 MFMA GEMM, 3-buffer counted-vmcnt pipeline (T2/T3/T4/T5) ----
// C = A[M,K] @ Bt[N,K]^T. BN=128 (2x2 waves of 64x64, 48KB LDS -> 3 blocks/CU)
// or BN=64 (4 waves of 32x64 stacked along M, 36KB LDS).
// 3 LDS buffers, prefetch 2 K-tiles ahead, ONE barrier per K-step, wait vmcnt(CPW)
// (t+1's loads done; t+2's CPW loads stay in flight across the barrier). Tail peeled.
// T2 swizzle: stored slot = slot ^ ((row>>1)&3) via pre-swizzled global source.
template <int EPI, int BN>
__global__ __launch_bounds__(256) void k_gemm(
    const unsigned short* __restrict__ A, const unsigned short* __restrict__ Bt,
    const float* __restrict__ bias, const float* __restrict__ resid,
    float* __restrict__ outf, unsigned short* __restrict__ outb,
    int M, int N, int K) {
  constexpr int BCH = BN / 16;
  constexpr int CHUNKS = 8 + BCH;
  constexpr int CPW = CHUNKS / 4;
  constexpr int MI = (BN == 128) ? 4 : 2;
  constexpr int NJ = 4;
  __shared__ unsigned short lA[3][128 * 32];
  __shared__ unsigned short lB[3][BN * 32];
  int tid = threadIdx.x;
  int nwg = gridDim.x * gridDim.y;
  int bid = blockIdx.y * gridDim.x + blockIdx.x;
  int swz = (bid & 7) * (nwg >> 3) + (bid >> 3);
  int m0 = (swz / gridDim.x) * 128, n0 = (swz % gridDim.x) * BN;
  int lane = tid & 63, w = tid >> 6;
  int wm = (BN == 128) ? (w >> 1) * 64 : w * 32;
  int wn = (BN == 128) ? (w & 1) * 64 : 0;
  int lr = lane & 15, lg = lane >> 4;
  f32x4 acc[MI][NJ] = {};
  int scol = ((lane & 3) ^ ((lane >> 3) & 3)) * 8;
  const unsigned short* gsrc[CPW];
  int loff[CPW];
  bool isa[CPW];
#pragma unroll
  for (int c0 = 0; c0 < CPW; c0++) {
    int c = w * CPW + c0;
    if (c < 8) {
      int row = c * 16 + (lane >> 2);
      gsrc[c0] = A + (size_t)(m0 + row) * K + scol;
      loff[c0] = c * 512;
      isa[c0] = true;
    } else {
      int row = (c - 8) * 16 + (lane >> 2);
      gsrc[c0] = Bt + (size_t)(n0 + row) * K + scol;
      loff[c0] = (c - 8) * 512;
      isa[c0] = false;
    }
  }
  auto stage = [&](int k0, int buf) {
#pragma unroll
    for (int c0 = 0; c0 < CPW; c0++)
      gload_lds16(gsrc[c0] + k0, isa[c0] ? &lA[buf][loff[c0]] : &lB[buf][loff[c0]]);
  };
  int fcol = (lg ^ ((lr >> 1) & 3)) * 8;
  auto compute = [&](int buf) {
    bf16x8 af[MI], bfr[NJ];
#pragma unroll
    for (int i = 0; i < MI; i++)
      af[i] = *(const bf16x8*)&lA[buf][(wm + i * 16 + lr) * 32 + fcol];
#pragma unroll
    for (int j = 0; j < NJ; j++)
      bfr[j] = *(const bf16x8*)&lB[buf][(wn + j * 16 + lr) * 32 + fcol];
    __builtin_amdgcn_s_setprio(1);
#pragma unroll
    for (int i = 0; i < MI; i++)
#pragma unroll
      for (int j = 0; j < NJ; j++)
        acc[i][j] = MFMA16(af[i], bfr[j], acc[i][j]);
    __builtin_amdgcn_s_setprio(0);
  };
  int nt = K >> 5;  // nt >= 32 for all our shapes
  stage(0, 0);
  stage(32, 1);
  wait_vmcnt<CPW>();  // tile 0 landed; tile 1's CPW loads may be in flight
  __builtin_amdgcn_s_barrier();
  int c0 = 0, c1 = 1, c2 = 2;
  for (int t = 0; t < nt - 2; t++) {
    stage((t + 2) * 32, c2);
    compute(c0);
    wait_vmcnt<CPW>();  // t+1's loads done; t+2's stay in flight
    __builtin_amdgcn_s_barrier();
    int tmp = c0; c0 = c1; c1 = c2; c2 = tmp;
  }
  compute(c0);
  wait_vmcnt<0>();
  __builtin_amdgcn_s_barrier();
  compute(c1);
#pragma unroll
  for (int i = 0; i < MI; i++) {
#pragma unroll
    for (int j = 0; j < NJ; j++) {
      int colb = n0 + wn + j * 16 + lr;
      float bv = bias[colb];
#pragma unroll
      for (int r = 0; r < 4; r++) {
        int row = m0 + wm + i * 16 + lg * 4 + r;
        float v = acc[i][j][r] + bv;
        size_t idx = (size_t)row * N + colb;
        if constexpr (EPI == 0) {
          outb[idx] = f2bf(v);
        } else if constexpr (EPI == 1) {
          outf[idx] = v + resid[idx];
        } else {
          float gv = 0.5f * v * (1.0f + erff(v * 0.70710678118654752f));
          outb[idx] = f2bf(gv);
        }
      }
    }
  }
}

// ---------------- causal flash attention ----------------
__global__ __launch_bounds__(256) void k_attention(
    const unsigned short* __restrict__ qkv, const unsigned short* __restrict__ Vt,
    unsigned short* __restrict__ out) {
  __shared__ unsigned short lK[2][64 * 64];
  __shared__ unsigned short lV[2][64 * 64];
  __shared__ unsigned short lP[4][16][72];
  int bid = blockIdx.x;
  int i = bid >> 3;
  int qt = 31 - (i >> 2);
  int bh = (bid & 7) * 4 + (i & 3);
  int b = bh >> 4, h = bh & 15;
  int tid = threadIdx.x, lane = tid & 63, w = tid >> 6;
  int lr = lane & 15, lg = lane >> 4;
  const unsigned short* base = qkv + (size_t)b * SEQ * THREE_EMBED + h * HDIM;
  const unsigned short* Kb = base + EMBED;
  const unsigned short* Vb = Vt + (size_t)bh * HDIM * SEQ;
  int q0 = qt * 64 + w * 16;
  bf16x8 qf[2];
  {
    int qrow = q0 + lr;
    qf[0] = *(const bf16x8*)(base + (size_t)qrow * THREE_EMBED + lg * 8);
    qf[1] = *(const bf16x8*)(base + (size_t)qrow * THREE_EMBED + 32 + lg * 8);
  }
  bf16x8 ones;
  {
    short o1 = 0x3F80;
#pragma unroll
    for (int j = 0; j < 8; j++) ones[j] = o1;
  }
  f32x4 o[4] = {};
  f32x4 osum = {};
  float m_[4] = {-INFINITY, -INFINITY, -INFINITY, -INFINITY};
  int srow = lane >> 3;
  int scol = ((lane & 7) ^ (lane >> 3)) * 8;
  const float SCL = 0.125f * 1.4426950408889634f;
  int nkv = qt + 1;
  auto stage = [&](int kt, int cur) {
#pragma unroll
    for (int c = 0; c < 2; c++) {
      int chunk = w * 2 + c;
      int row = chunk * 8 + srow;
      gload_lds16(Kb + (size_t)(kt * 64 + row) * THREE_EMBED + scol, &lK[cur][chunk * 512]);
      gload_lds16(Vb + (size_t)row * SEQ + kt * 64 + scol, &lV[cur][chunk * 512]);
    }
  };
  stage(0, 0);
  wait_vm0_barrier();
  int cur = 0;
  for (int kt = 0; kt < nkv; kt++) {
    if (kt + 1 < nkv) stage(kt + 1, cur ^ 1);
    __builtin_amdgcn_s_setprio(1);
    f32x4 s[4];
#pragma unroll
    for (int ct = 0; ct < 4; ct++) {
      int krow = ct * 16 + lr;
      int sw = (krow & 7) << 3;
      bf16x8 k0 = *(const bf16x8*)&lK[cur][krow * 64 + ((lg * 8) ^ sw)];
      bf16x8 k1 = *(const bf16x8*)&lK[cur][krow * 64 + ((32 + lg * 8) ^ sw)];
      f32x4 z = {};
      z = MFMA16(qf[0], k0, z);
      s[ct] = MFMA16(qf[1], k1, z);
    }
    __builtin_amdgcn_s_setprio(0);
    bool maskt = (kt * 64 + 63 > q0);
    float pm[4] = {-INFINITY, -INFINITY, -INFINITY, -INFINITY};
#pragma unroll
    for (int ct = 0; ct < 4; ct++) {
#pragma unroll
      for (int r = 0; r < 4; r++) {
        float sv = s[ct][r] * SCL;
        if (maskt) {
          int kg = kt * 64 + ct * 16 + lr;
          int qg = q0 + lg * 4 + r;
          if (kg > qg) sv = -INFINITY;
        }
        s[ct][r] = sv;
        pm[r] = fmaxf(pm[r], sv);
      }
    }
    float dm = fmaxf(fmaxf(pm[0] - m_[0], pm[1] - m_[1]),
                     fmaxf(pm[2] - m_[2], pm[3] - m_[3]));
    if (!__all(dm <= 8.0f)) {
#pragma unroll
      for (int r = 0; r < 4; r++) {
        float mx = pm[r];
        mx = fmaxf(mx, __shfl_xor(mx, 1));
        mx = fmaxf(mx, __shfl_xor(mx, 2));
        mx = fmaxf(mx, __shfl_xor(mx, 4));
        mx = fmaxf(mx, __shfl_xor(mx, 8));
        float mn = fmaxf(m_[r], mx);
        float al = exp2f(m_[r] - mn);
        m_[r] = mn;
        osum[r] *= al;
#pragma unroll
        for (int dt = 0; dt < 4; dt++) o[dt][r] *= al;
      }
    }
#pragma unroll
    for (int ct = 0; ct < 4; ct++)
#pragma unroll
      for (int r = 0; r < 4; r++)
        lP[w][lg * 4 + r][ct * 16 + lr] = f2bf(exp2f(s[ct][r] - m_[r]));
    __builtin_amdgcn_s_setprio(1);
#pragma unroll
    for (int ks = 0; ks < 2; ks++) {
      bf16x8 pf = *(const bf16x8*)&lP[w][lr][ks * 32 + lg * 8];
      osum = MFMA16(pf, ones, osum);
#pragma unroll
      for (int dt = 0; dt < 4; dt++) {
        int vrow = dt * 16 + lr;
        int sw = (vrow & 7) << 3;
        bf16x8 vf = *(const bf16x8*)&lV[cur][vrow * 64 + ((ks * 32 + lg * 8) ^ sw)];
        o[dt] = MFMA16(pf, vf, o[dt]);
      }
    }
    __builtin_amdgcn_s_setprio(0);
    wait_vm0_barrier();
    cur ^= 1;
  }
#pragma unroll
  for (int dt = 0; dt < 4; dt++)
#pragma unroll
    for (int r = 0; r < 4; r++) {
      int row = q0 + lg * 4 + r;
      float val = o[dt][r] / osum[r];
      out[(size_t)(b * SEQ + row) * EMBED + h * HDIM + dt * 16 + lr] = f2bf(val);
    }
}

extern "C" void kernel_launch(void* const* d_in, const int* in_sizes, int n_in,
                              void* d_out, int out_size, void* d_ws, size_t ws_size,
                              hipStream_t stream) {
  const float* x      = (const float*)d_in[0];
  const float* ln1_g  = (const float*)d_in[1];
  const float* ln1_b  = (const float*)d_in[2];
  const float* w_attn = (const float*)d_in[3];
  const float* b_attn = (const float*)d_in[4];
  const float* w_proj = (const float*)d_in[5];
  const float* b_proj = (const float*)d_in[6];
  const float* ln2_g  = (const float*)d_in[7];
  const float* ln2_b  = (const float*)d_in[8];
  const float* w_fc   = (const float*)d_in[9];
  const float* b_fc   = (const float*)d_in[10];
  const float* w_fc2  = (const float*)d_in[11];
  const float* b_fc2  = (const float*)d_in[12];
  float* outp = (float*)d_out;

  char* ws = (char*)d_ws;
  unsigned short* wT_attn = (unsigned short*)(ws);             // [3072][1024] bf16, 6 MB
  unsigned short* wT_proj = (unsigned short*)(ws + 6291456);   // [1024][1024] bf16, 2 MB
  unsigned short* wT_fc   = (unsigned short*)(ws + 8388608);   // [4096][1024] bf16, 8 MB
  unsigned short* wT_fc2  = (unsigned short*)(ws + 16777216);  // [1024][4096] bf16, 8 MB
  unsigned short* buf1    = (unsigned short*)(ws + 25165824);  // 8 MB: xln -> attnout -> x2ln
  float*          x1      = (float*)(ws + 33554432);           // 16 MB fp32 (written after attention)
  unsigned short* Vt      = (unsigned short*)(ws + 33554432);  // 8 MB bf16, dead once attention done
  unsigned short* qkv_h   = (unsigned short*)(ws + 50331648);  // 24 MB qkv -> 32 MB h (48..80 MB)

  dim3 blk(256);
  k_transpose_bf16<<<dim3(3072 / 32, 1024 / 32), blk, 0, stream>>>(w_attn, wT_attn, 1024, 3072);
  k_transpose_bf16<<<dim3(1024 / 32, 1024 / 32), blk, 0, stream>>>(w_proj, wT_proj, 1024, 1024);
  k_transpose_bf16<<<dim3(4096 / 32, 1024 / 32), blk, 0, stream>>>(w_fc, wT_fc, 1024, 4096);
  k_transpose_bf16<<<dim3(1024 / 32, 4096 / 32), blk, 0, stream>>>(w_fc2, wT_fc2, 4096, 1024);
  // LN1: x -> xln (buf1)
  k_layernorm<<<dim3(MTOT), blk, 0, stream>>>(x, ln1_g, ln1_b, buf1);
  // QKV: 3-buf BN=128, 24x32 = 768 blocks
  k_gemm<0, 128><<<dim3(THREE_EMBED / 128, MTOT / 128), blk, 0, stream>>>(
      buf1, wT_attn, b_attn, nullptr, nullptr, qkv_h, MTOT, THREE_EMBED, EMBED);
  // V transpose for attention
  k_transpose_v<<<dim3(SEQ / 32, 2 * BATCH * HEADS), blk, 0, stream>>>(qkv_h, Vt);
  // attention -> attnout (buf1)
  k_attention<<<dim3(1024), blk, 0, stream>>>(qkv_h, Vt, buf1);
  // proj + residual: 3-buf BN=64, 512 blocks (overwrites Vt region — Vt dead)
  k_gemm<1, 64><<<dim3(EMBED / 64, MTOT / 128), blk, 0, stream>>>(
      buf1, wT_proj, b_proj, x, x1, nullptr, MTOT, EMBED, EMBED);
  // LN2: x1 -> x2ln (buf1)
  k_layernorm<<<dim3(MTOT), blk, 0, stream>>>(x1, ln2_g, ln2_b, buf1);
  // FC1 + GELU: 3-buf BN=128, 32x32 = 1024 blocks
  k_gemm<2, 128><<<dim3(4 * EMBED / 128, MTOT / 128), blk, 0, stream>>>(
      buf1, wT_fc, b_fc, nullptr, nullptr, qkv_h, MTOT, 4 * EMBED, EMBED);
  // FC2 + residual -> out: 3-buf BN=64, 512 blocks
  k_gemm<1, 64><<<dim3(EMBED / 64, MTOT / 128), blk, 0, stream>>>(
      qkv_h, wT_fc2, b_fc2, x1, outp, nullptr, MTOT, EMBED, 4 * EMBED);
}

// Round 10
// 256.182 us; speedup vs baseline: 1.0930x; 1.0930x over previous
//
#include <hip/hip_runtime.h>

#define EMBED 1024
#define THREE_EMBED 3072
#define HEADS 16
#define HDIM 64
#define SEQ 2048
#define BATCH 2
#define MTOT 4096  // B*T

typedef short bf16x8 __attribute__((ext_vector_type(8)));
typedef float f32x4 __attribute__((ext_vector_type(4)));

#define MFMA16(a, b, c) __builtin_amdgcn_mfma_f32_16x16x32_bf16(a, b, c, 0, 0, 0)

__device__ __forceinline__ unsigned short f2bf(float f) {
  union { float f; unsigned int u; } v; v.f = f;
  unsigned int r = v.u + 0x7fffu + ((v.u >> 16) & 1u);
  return (unsigned short)(r >> 16);
}

// async 16B global->LDS. LDS dest is wave-uniform base + lane*16 (HW semantics).
__device__ __forceinline__ void gload_lds16(const unsigned short* g, unsigned short* l) {
  __builtin_amdgcn_global_load_lds(
      (const __attribute__((address_space(1))) void*)g,
      (__attribute__((address_space(3))) void*)l, 16, 0, 0);
}

__device__ __forceinline__ void wait_vm0_barrier() {
  asm volatile("s_waitcnt vmcnt(0)" ::: "memory");
  __builtin_amdgcn_s_barrier();
}

template <int N>
__device__ __forceinline__ void wait_vmcnt() {
  if constexpr (N == 0) asm volatile("s_waitcnt vmcnt(0)" ::: "memory");
  else if constexpr (N == 1) asm volatile("s_waitcnt vmcnt(1)" ::: "memory");
  else if constexpr (N == 2) asm volatile("s_waitcnt vmcnt(2)" ::: "memory");
  else if constexpr (N == 3) asm volatile("s_waitcnt vmcnt(3)" ::: "memory");
  else if constexpr (N == 4) asm volatile("s_waitcnt vmcnt(4)" ::: "memory");
  else if constexpr (N == 6) asm volatile("s_waitcnt vmcnt(6)" ::: "memory");
  else if constexpr (N == 8) asm volatile("s_waitcnt vmcnt(8)" ::: "memory");
}

__device__ __forceinline__ void open_phase_barrier() {
  __builtin_amdgcn_s_barrier();
  __builtin_amdgcn_sched_barrier(0);  // keep ds_reads below the barrier (rule #18)
}

// ---------------- transpose fp32 [K][N] -> bf16 [N][K] ----------------
__global__ __launch_bounds__(256) void k_transpose_bf16(
    const float* __restrict__ in, unsigned short* __restrict__ out, int K, int N) {
  __shared__ float t[32][33];
  int tx = threadIdx.x & 31, ty = threadIdx.x >> 5;
  int n0 = blockIdx.x * 32, k0 = blockIdx.y * 32;
#pragma unroll
  for (int i = 0; i < 32; i += 8)
    t[ty + i][tx] = in[(size_t)(k0 + ty + i) * N + n0 + tx];
  __syncthreads();
#pragma unroll
  for (int i = 0; i < 32; i += 8)
    out[(size_t)(n0 + ty + i) * K + k0 + tx] = f2bf(t[tx][ty + i]);
}

// ---------------- V transpose: qkv V-part -> Vt[bh][64][2048] bf16 ----------------
__global__ __launch_bounds__(256) void k_transpose_v(
    const unsigned short* __restrict__ qkv, unsigned short* __restrict__ Vt) {
  __shared__ unsigned short t[32][33];
  int tx = threadIdx.x & 31, ty = threadIdx.x >> 5;  // 32 x 8
  int t0 = blockIdx.x * 32;
  int d0 = (blockIdx.y & 1) * 32;
  int bh = blockIdx.y >> 1;
  int b = bh >> 4, h = bh & 15;
  const unsigned short* src = qkv + (size_t)b * SEQ * THREE_EMBED + 2 * EMBED + h * HDIM;
#pragma unroll
  for (int i = 0; i < 32; i += 8)
    t[ty + i][tx] = src[(size_t)(t0 + ty + i) * THREE_EMBED + d0 + tx];
  __syncthreads();
  unsigned short* dst = Vt + (size_t)bh * HDIM * SEQ;
#pragma unroll
  for (int i = 0; i < 32; i += 8)
    dst[(size_t)(d0 + ty + i) * SEQ + t0 + tx] = t[tx][ty + i];
}

// ---------------- layernorm fp32 [4096][1024] -> bf16 ----------------
__global__ __launch_bounds__(256) void k_layernorm(
    const float* __restrict__ x, const float* __restrict__ g,
    const float* __restrict__ b, unsigned short* __restrict__ out) {
  int row = blockIdx.x;
  int tid = threadIdx.x;
  const float4 xv = *(const float4*)(x + (size_t)row * EMBED + tid * 4);
  float s = xv.x + xv.y + xv.z + xv.w;
  float sq = xv.x * xv.x + xv.y * xv.y + xv.z * xv.z + xv.w * xv.w;
#pragma unroll
  for (int off = 1; off < 64; off <<= 1) {
    s += __shfl_xor(s, off);
    sq += __shfl_xor(sq, off);
  }
  __shared__ float red[8];
  int w = tid >> 6;
  if ((tid & 63) == 0) { red[w] = s; red[4 + w] = sq; }
  __syncthreads();
  s = red[0] + red[1] + red[2] + red[3];
  sq = red[4] + red[5] + red[6] + red[7];
  float mu = s * (1.0f / EMBED);
  float var = sq * (1.0f / EMBED) - mu * mu;
  float rs = rsqrtf(var + 1e-5f);
  float xs[4] = {xv.x, xv.y, xv.z, xv.w};
  unsigned short o[4];
#pragma unroll
  for (int c = 0; c < 4; c++) {
    int col = tid * 4 + c;
    o[c] = f2bf((xs[c] - mu) * rs * g[col] + b[col]);
  }
  *(ushort4*)(out + (size_t)row * EMBED + tid * 4) = *(const ushort4*)o;
}

// ======== 256x256 8-wave 4-phase GEMM v2 (register-held operands) ========
// C = A[M,K] @ Bt[N,K]^T, BK=64, dbuf LDS 128KB. Per wave: output 128x64 split-half
// (m-frags 0-3 in A-half0 rows, 4-7 in A-half1; n-frags 0-1 B-half0, 2-3 B-half1).
// LDS reads per K-tile per wave = 24 b128 (minimum): p1 rdB0+rdB1, p2 rdA1,
// p3 none, p4 prefetch next-tile A0. A/B quadrant frags held in regs across phases.
// Stage map (tile t stages t+1): p1->A0', p2->B0', p3->B1', p4->A1'; uniform
// vmcnt(4) => operand drained >=1 phase before its read (queue-sim verified).
// One barrier per phase + sched_barrier(0) (rule #18). Tail peeled vmcnt 2->0.
template <int EPI>
__global__ __launch_bounds__(512, 2) void k_gemm8(
    const unsigned short* __restrict__ A, const unsigned short* __restrict__ Bt,
    const float* __restrict__ bias, const float* __restrict__ resid,
    float* __restrict__ outf, unsigned short* __restrict__ outb,
    int M, int N, int K) {
  __shared__ unsigned short lA[2][16384];
  __shared__ unsigned short lB[2][16384];
  int tid = threadIdx.x;
  int nwg = gridDim.x * gridDim.y;
  int bid = blockIdx.y * gridDim.x + blockIdx.x;
  int swz = (bid & 7) * (nwg >> 3) + (bid >> 3);
  int m0 = (swz / gridDim.x) * 256, n0 = (swz % gridDim.x) * 256;
  int lane = tid & 63, w = tid >> 6;
  int lr = lane & 15, lg = lane >> 4;
  int warow = (w >> 2) * 64;  // A row base within a half
  int wbrow = (w & 3) * 32;   // B row base within a half
  int rx = lr & 7;
  int colk[2] = {(lg ^ rx) * 8, ((4 + lg) ^ rx) * 8};
  f32x4 acc[8][4] = {};
  int swzk = ((lane & 7) ^ ((lane >> 3) & 7)) * 8;  // pre-swizzled global col (shorts)
  const unsigned short* gA[2];
  const unsigned short* gB[2];
#pragma unroll
  for (int i = 0; i < 2; i++) {
    int chrow = (w * 2 + i) * 8 + (lane >> 3);
    gA[i] = A + (size_t)(m0 + chrow) * K + swzk;
    gB[i] = Bt + (size_t)(n0 + chrow) * K + swzk;
  }
  int NT = K >> 6;
  auto stageA = [&](int h, int kt, int buf) {
    size_t goff = (size_t)(h * 128) * K + (size_t)kt * 64;
    int lo = h * 8192 + w * 1024;
    gload_lds16(gA[0] + goff, &lA[buf][lo]);
    gload_lds16(gA[1] + goff, &lA[buf][lo + 512]);
  };
  auto stageB = [&](int h, int kt, int buf) {
    size_t goff = (size_t)(h * 128) * K + (size_t)kt * 64;
    int lo = h * 8192 + w * 1024;
    gload_lds16(gB[0] + goff, &lB[buf][lo]);
    gload_lds16(gB[1] + goff, &lB[buf][lo + 512]);
  };
  bf16x8 aX[4][2], aY[4][2], b0[2][2], b1[2][2];
  auto rdA = [&](int buf, int mh, bf16x8 (&dst)[4][2]) {
#pragma unroll
    for (int ii = 0; ii < 4; ii++) {
      int ra = mh * 128 + warow + ii * 16 + lr;
#pragma unroll
      for (int ks = 0; ks < 2; ks++)
        dst[ii][ks] = *(const bf16x8*)&lA[buf][ra * 64 + colk[ks]];
    }
  };
  auto rdB = [&](int buf, int nh, bf16x8 (&dst)[2][2]) {
#pragma unroll
    for (int jj = 0; jj < 2; jj++) {
      int rb = nh * 128 + wbrow + jj * 16 + lr;
#pragma unroll
      for (int ks = 0; ks < 2; ks++)
        dst[jj][ks] = *(const bf16x8*)&lB[buf][rb * 64 + colk[ks]];
    }
  };
  auto mf = [&](int mh, int nh, bf16x8 (&aa)[4][2], bf16x8 (&bb)[2][2]) {
    __builtin_amdgcn_s_setprio(1);
#pragma unroll
    for (int ii = 0; ii < 4; ii++)
#pragma unroll
      for (int jj = 0; jj < 2; jj++)
#pragma unroll
        for (int ks = 0; ks < 2; ks++)
          acc[mh * 4 + ii][nh * 2 + jj] =
              MFMA16(aa[ii][ks], bb[jj][ks], acc[mh * 4 + ii][nh * 2 + jj]);
    __builtin_amdgcn_s_setprio(0);
  };
  // prologue: stage tile 0 (A0,B0,B1,A1), drain A0, read its frags
  stageA(0, 0, 0); stageB(0, 0, 0); stageB(1, 0, 0); stageA(1, 0, 0);
  wait_vmcnt<6>();
  open_phase_barrier();
  rdA(0, 0, aX);
  for (int t = 0; t < NT - 1; t++) {
    int cur = t & 1, nxt = cur ^ 1;
    // p1: stage A0(t+1); read B0,B1(t); mfma A0*B0
    stageA(0, t + 1, nxt);
    wait_vmcnt<4>();
    open_phase_barrier();
    rdB(cur, 0, b0);
    rdB(cur, 1, b1);
    mf(0, 0, aX, b0);
    // p2: stage B0(t+1); read A1(t); mfma A0*B1
    stageB(0, t + 1, nxt);
    wait_vmcnt<4>();
    open_phase_barrier();
    rdA(cur, 1, aY);
    mf(0, 1, aX, b1);
    // p3: stage B1(t+1); mfma A1*B1
    stageB(1, t + 1, nxt);
    wait_vmcnt<4>();
    open_phase_barrier();
    mf(1, 1, aY, b1);
    // p4: stage A1(t+1); prefetch-read A0(t+1); mfma A1*B0
    stageA(1, t + 1, nxt);
    wait_vmcnt<4>();
    open_phase_barrier();
    rdA(nxt, 0, aX);
    mf(1, 0, aY, b0);
  }
  {  // tail tile NT-1 (no staging), tightening drains
    int cur = (NT - 1) & 1;
    wait_vmcnt<2>();
    open_phase_barrier();
    rdB(cur, 0, b0);
    rdB(cur, 1, b1);
    mf(0, 0, aX, b0);
    wait_vmcnt<0>();
    open_phase_barrier();
    rdA(cur, 1, aY);
    mf(0, 1, aX, b1);
    mf(1, 1, aY, b1);
    mf(1, 0, aY, b0);
  }
  // epilogue (split-half output mapping)
#pragma unroll
  for (int i = 0; i < 8; i++) {
#pragma unroll
    for (int j = 0; j < 4; j++) {
      int col = n0 + (j >> 1) * 128 + wbrow + (j & 1) * 16 + lr;
      float bv = bias[col];
#pragma unroll
      for (int r = 0; r < 4; r++) {
        int row = m0 + (i >> 2) * 128 + warow + (i & 3) * 16 + lg * 4 + r;
        float v = acc[i][j][r] + bv;
        size_t idx = (size_t)row * N + col;
        if constexpr (EPI == 0) {
          outb[idx] = f2bf(v);
        } else if constexpr (EPI == 1) {
          outf[idx] = v + resid[idx];
        } else {
          float gv = 0.5f * v * (1.0f + erff(v * 0.70710678118654752f));
          outb[idx] = f2bf(gv);
        }
      }
    }
  }
}

// ---- bf16 MFMA GEMM, 3-buffer counted-vmcnt pipeline (narrow tiles) ----
template <int EPI, int BN>
__global__ __launch_bounds__(256) void k_gemm(
    const unsigned short* __restrict__ A, const unsigned short* __restrict__ Bt,
    const float* __restrict__ bias, const float* __restrict__ resid,
    float* __restrict__ outf, unsigned short* __restrict__ outb,
    int M, int N, int K) {
  constexpr int BCH = BN / 16;
  constexpr int CHUNKS = 8 + BCH;
  constexpr int CPW = CHUNKS / 4;
  constexpr int MI = (BN == 128) ? 4 : 2;
  constexpr int NJ = 4;
  __shared__ unsigned short lA[3][128 * 32];
  __shared__ unsigned short lB[3][BN * 32];
  int tid = threadIdx.x;
  int nwg = gridDim.x * gridDim.y;
  int bid = blockIdx.y * gridDim.x + blockIdx.x;
  int swz = (bid & 7) * (nwg >> 3) + (bid >> 3);
  int m0 = (swz / gridDim.x) * 128, n0 = (swz % gridDim.x) * BN;
  int lane = tid & 63, w = tid >> 6;
  int wm = (BN == 128) ? (w >> 1) * 64 : w * 32;
  int wn = (BN == 128) ? (w & 1) * 64 : 0;
  int lr = lane & 15, lg = lane >> 4;
  f32x4 acc[MI][NJ] = {};
  int scol = ((lane & 3) ^ ((lane >> 3) & 3)) * 8;
  const unsigned short* gsrc[CPW];
  int loff[CPW];
  bool isa[CPW];
#pragma unroll
  for (int c0 = 0; c0 < CPW; c0++) {
    int c = w * CPW + c0;
    if (c < 8) {
      int row = c * 16 + (lane >> 2);
      gsrc[c0] = A + (size_t)(m0 + row) * K + scol;
      loff[c0] = c * 512;
      isa[c0] = true;
    } else {
      int row = (c - 8) * 16 + (lane >> 2);
      gsrc[c0] = Bt + (size_t)(n0 + row) * K + scol;
      loff[c0] = (c - 8) * 512;
      isa[c0] = false;
    }
  }
  auto stage = [&](int k0, int buf) {
#pragma unroll
    for (int c0 = 0; c0 < CPW; c0++)
      gload_lds16(gsrc[c0] + k0, isa[c0] ? &lA[buf][loff[c0]] : &lB[buf][loff[c0]]);
  };
  int fcol = (lg ^ ((lr >> 1) & 3)) * 8;
  auto compute = [&](int buf) {
    bf16x8 af[MI], bfr[NJ];
#pragma unroll
    for (int i = 0; i < MI; i++)
      af[i] = *(const bf16x8*)&lA[buf][(wm + i * 16 + lr) * 32 + fcol];
#pragma unroll
    for (int j = 0; j < NJ; j++)
      bfr[j] = *(const bf16x8*)&lB[buf][(wn + j * 16 + lr) * 32 + fcol];
    __builtin_amdgcn_s_setprio(1);
#pragma unroll
    for (int i = 0; i < MI; i++)
#pragma unroll
      for (int j = 0; j < NJ; j++)
        acc[i][j] = MFMA16(af[i], bfr[j], acc[i][j]);
    __builtin_amdgcn_s_setprio(0);
  };
  int nt = K >> 5;
  stage(0, 0);
  stage(32, 1);
  wait_vmcnt<CPW>();
  __builtin_amdgcn_s_barrier();
  int c0 = 0, c1 = 1, c2 = 2;
  for (int t = 0; t < nt - 2; t++) {
    stage((t + 2) * 32, c2);
    compute(c0);
    wait_vmcnt<CPW>();
    __builtin_amdgcn_s_barrier();
    int tmp = c0; c0 = c1; c1 = c2; c2 = tmp;
  }
  compute(c0);
  wait_vmcnt<0>();
  __builtin_amdgcn_s_barrier();
  compute(c1);
#pragma unroll
  for (int i = 0; i < MI; i++) {
#pragma unroll
    for (int j = 0; j < NJ; j++) {
      int colb = n0 + wn + j * 16 + lr;
      float bv = bias[colb];
#pragma unroll
      for (int r = 0; r < 4; r++) {
        int row = m0 + wm + i * 16 + lg * 4 + r;
        float v = acc[i][j][r] + bv;
        size_t idx = (size_t)row * N + colb;
        if constexpr (EPI == 0) {
          outb[idx] = f2bf(v);
        } else if constexpr (EPI == 1) {
          outf[idx] = v + resid[idx];
        } else {
          float gv = 0.5f * v * (1.0f + erff(v * 0.70710678118654752f));
          outb[idx] = f2bf(gv);
        }
      }
    }
  }
}

// ---------------- causal flash attention ----------------
__global__ __launch_bounds__(256) void k_attention(
    const unsigned short* __restrict__ qkv, const unsigned short* __restrict__ Vt,
    unsigned short* __restrict__ out) {
  __shared__ unsigned short lK[2][64 * 64];
  __shared__ unsigned short lV[2][64 * 64];
  __shared__ unsigned short lP[4][16][72];
  int bid = blockIdx.x;
  int i = bid >> 3;
  int qt = 31 - (i >> 2);
  int bh = (bid & 7) * 4 + (i & 3);
  int b = bh >> 4, h = bh & 15;
  int tid = threadIdx.x, lane = tid & 63, w = tid >> 6;
  int lr = lane & 15, lg = lane >> 4;
  const unsigned short* base = qkv + (size_t)b * SEQ * THREE_EMBED + h * HDIM;
  const unsigned short* Kb = base + EMBED;
  const unsigned short* Vb = Vt + (size_t)bh * HDIM * SEQ;
  int q0 = qt * 64 + w * 16;
  bf16x8 qf[2];
  {
    int qrow = q0 + lr;
    qf[0] = *(const bf16x8*)(base + (size_t)qrow * THREE_EMBED + lg * 8);
    qf[1] = *(const bf16x8*)(base + (size_t)qrow * THREE_EMBED + 32 + lg * 8);
  }
  bf16x8 ones;
  {
    short o1 = 0x3F80;
#pragma unroll
    for (int j = 0; j < 8; j++) ones[j] = o1;
  }
  f32x4 o[4] = {};
  f32x4 osum = {};
  float m_[4] = {-INFINITY, -INFINITY, -INFINITY, -INFINITY};
  int srow = lane >> 3;
  int scol = ((lane & 7) ^ (lane >> 3)) * 8;
  const float SCL = 0.125f * 1.4426950408889634f;
  int nkv = qt + 1;
  auto stage = [&](int kt, int cur) {
#pragma unroll
    for (int c = 0; c < 2; c++) {
      int chunk = w * 2 + c;
      int row = chunk * 8 + srow;
      gload_lds16(Kb + (size_t)(kt * 64 + row) * THREE_EMBED + scol, &lK[cur][chunk * 512]);
      gload_lds16(Vb + (size_t)row * SEQ + kt * 64 + scol, &lV[cur][chunk * 512]);
    }
  };
  stage(0, 0);
  wait_vm0_barrier();
  int cur = 0;
  for (int kt = 0; kt < nkv; kt++) {
    if (kt + 1 < nkv) stage(kt + 1, cur ^ 1);
    __builtin_amdgcn_s_setprio(1);
    f32x4 s[4];
#pragma unroll
    for (int ct = 0; ct < 4; ct++) {
      int krow = ct * 16 + lr;
      int sw = (krow & 7) << 3;
      bf16x8 k0 = *(const bf16x8*)&lK[cur][krow * 64 + ((lg * 8) ^ sw)];
      bf16x8 k1 = *(const bf16x8*)&lK[cur][krow * 64 + ((32 + lg * 8) ^ sw)];
      f32x4 z = {};
      z = MFMA16(qf[0], k0, z);
      s[ct] = MFMA16(qf[1], k1, z);
    }
    __builtin_amdgcn_s_setprio(0);
    bool maskt = (kt * 64 + 63 > q0);
    float pm[4] = {-INFINITY, -INFINITY, -INFINITY, -INFINITY};
#pragma unroll
    for (int ct = 0; ct < 4; ct++) {
#pragma unroll
      for (int r = 0; r < 4; r++) {
        float sv = s[ct][r] * SCL;
        if (maskt) {
          int kg = kt * 64 + ct * 16 + lr;
          int qg = q0 + lg * 4 + r;
          if (kg > qg) sv = -INFINITY;
        }
        s[ct][r] = sv;
        pm[r] = fmaxf(pm[r], sv);
      }
    }
    float dm = fmaxf(fmaxf(pm[0] - m_[0], pm[1] - m_[1]),
                     fmaxf(pm[2] - m_[2], pm[3] - m_[3]));
    if (!__all(dm <= 8.0f)) {
#pragma unroll
      for (int r = 0; r < 4; r++) {
        float mx = pm[r];
        mx = fmaxf(mx, __shfl_xor(mx, 1));
        mx = fmaxf(mx, __shfl_xor(mx, 2));
        mx = fmaxf(mx, __shfl_xor(mx, 4));
        mx = fmaxf(mx, __shfl_xor(mx, 8));
        float mn = fmaxf(m_[r], mx);
        float al = exp2f(m_[r] - mn);
        m_[r] = mn;
        osum[r] *= al;
#pragma unroll
        for (int dt = 0; dt < 4; dt++) o[dt][r] *= al;
      }
    }
#pragma unroll
    for (int ct = 0; ct < 4; ct++)
#pragma unroll
      for (int r = 0; r < 4; r++)
        lP[w][lg * 4 + r][ct * 16 + lr] = f2bf(exp2f(s[ct][r] - m_[r]));
    __builtin_amdgcn_s_setprio(1);
#pragma unroll
    for (int ks = 0; ks < 2; ks++) {
      bf16x8 pf = *(const bf16x8*)&lP[w][lr][ks * 32 + lg * 8];
      osum = MFMA16(pf, ones, osum);
#pragma unroll
      for (int dt = 0; dt < 4; dt++) {
        int vrow = dt * 16 + lr;
        int sw = (vrow & 7) << 3;
        bf16x8 vf = *(const bf16x8*)&lV[cur][vrow * 64 + ((ks * 32 + lg * 8) ^ sw)];
        o[dt] = MFMA16(pf, vf, o[dt]);
      }
    }
    __builtin_amdgcn_s_setprio(0);
    wait_vm0_barrier();
    cur ^= 1;
  }
#pragma unroll
  for (int dt = 0; dt < 4; dt++)
#pragma unroll
    for (int r = 0; r < 4; r++) {
      int row = q0 + lg * 4 + r;
      float val = o[dt][r] / osum[r];
      out[(size_t)(b * SEQ + row) * EMBED + h * HDIM + dt * 16 + lr] = f2bf(val);
    }
}

extern "C" void kernel_launch(void* const* d_in, const int* in_sizes, int n_in,
                              void* d_out, int out_size, void* d_ws, size_t ws_size,
                              hipStream_t stream) {
  const float* x      = (const float*)d_in[0];
  const float* ln1_g  = (const float*)d_in[1];
  const float* ln1_b  = (const float*)d_in[2];
  const float* w_attn = (const float*)d_in[3];
  const float* b_attn = (const float*)d_in[4];
  const float* w_proj = (const float*)d_in[5];
  const float* b_proj = (const float*)d_in[6];
  const float* ln2_g  = (const float*)d_in[7];
  const float* ln2_b  = (const float*)d_in[8];
  const float* w_fc   = (const float*)d_in[9];
  const float* b_fc   = (const float*)d_in[10];
  const float* w_fc2  = (const float*)d_in[11];
  const float* b_fc2  = (const float*)d_in[12];
  float* outp = (float*)d_out;

  char* ws = (char*)d_ws;
  unsigned short* wT_attn = (unsigned short*)(ws);             // [3072][1024] bf16, 6 MB
  unsigned short* wT_proj = (unsigned short*)(ws + 6291456);   // [1024][1024] bf16, 2 MB
  unsigned short* wT_fc   = (unsigned short*)(ws + 8388608);   // [4096][1024] bf16, 8 MB
  unsigned short* wT_fc2  = (unsigned short*)(ws + 16777216);  // [1024][4096] bf16, 8 MB
  unsigned short* buf1    = (unsigned short*)(ws + 25165824);  // 8 MB: xln -> attnout -> x2ln
  float*          x1      = (float*)(ws + 33554432);           // 16 MB fp32 (written after attention)
  unsigned short* Vt      = (unsigned short*)(ws + 33554432);  // 8 MB bf16, dead once attention done
  unsigned short* qkv_h   = (unsigned short*)(ws + 50331648);  // 24 MB qkv -> 32 MB h (48..80 MB)

  dim3 blk(256);
  k_transpose_bf16<<<dim3(3072 / 32, 1024 / 32), blk, 0, stream>>>(w_attn, wT_attn, 1024, 3072);
  k_transpose_bf16<<<dim3(1024 / 32, 1024 / 32), blk, 0, stream>>>(w_proj, wT_proj, 1024, 1024);
  k_transpose_bf16<<<dim3(4096 / 32, 1024 / 32), blk, 0, stream>>>(w_fc, wT_fc, 1024, 4096);
  k_transpose_bf16<<<dim3(1024 / 32, 4096 / 32), blk, 0, stream>>>(w_fc2, wT_fc2, 4096, 1024);
  // LN1: x -> xln (buf1)
  k_layernorm<<<dim3(MTOT), blk, 0, stream>>>(x, ln1_g, ln1_b, buf1);
  // QKV: 256^2 v2, 12x16 = 192 blocks
  k_gemm8<0><<<dim3(THREE_EMBED / 256, MTOT / 256), dim3(512), 0, stream>>>(
      buf1, wT_attn, b_attn, nullptr, nullptr, qkv_h, MTOT, THREE_EMBED, EMBED);
  // V transpose for attention
  k_transpose_v<<<dim3(SEQ / 32, 2 * BATCH * HEADS), blk, 0, stream>>>(qkv_h, Vt);
  // attention -> attnout (buf1)
  k_attention<<<dim3(1024), blk, 0, stream>>>(qkv_h, Vt, buf1);
  // proj + residual: 3-buf BN=64, 512 blocks (overwrites Vt region — Vt dead)
  k_gemm<1, 64><<<dim3(EMBED / 64, MTOT / 128), blk, 0, stream>>>(
      buf1, wT_proj, b_proj, x, x1, nullptr, MTOT, EMBED, EMBED);
  // LN2: x1 -> x2ln (buf1)
  k_layernorm<<<dim3(MTOT), blk, 0, stream>>>(x1, ln2_g, ln2_b, buf1);
  // FC1 + GELU: 256^2 v2, 16x16 = 256 blocks
  k_gemm8<2><<<dim3(4 * EMBED / 256, MTOT / 256), dim3(512), 0, stream>>>(
      buf1, wT_fc, b_fc, nullptr, nullptr, qkv_h, MTOT, 4 * EMBED, EMBED);
  // FC2 + residual -> out: 3-buf BN=64, 512 blocks
  k_gemm<1, 64><<<dim3(EMBED / 64, MTOT / 128), blk, 0, stream>>>(
      qkv_h, wT_fc2, b_fc2, x1, outp, nullptr, MTOT, EMBED, 4 * EMBED);
}

// Round 11
// 241.841 us; speedup vs baseline: 1.1578x; 1.0593x over previous
//
#include <hip/hip_runtime.h>

#define EMBED 1024
#define THREE_EMBED 3072
#define HEADS 16
#define HDIM 64
#define SEQ 2048
#define BATCH 2
#define MTOT 4096  // B*T

typedef short bf16x8 __attribute__((ext_vector_type(8)));
typedef float f32x4 __attribute__((ext_vector_type(4)));

#define MFMA16(a, b, c) __builtin_amdgcn_mfma_f32_16x16x32_bf16(a, b, c, 0, 0, 0)

__device__ __forceinline__ unsigned short f2bf(float f) {
  union { float f; unsigned int u; } v; v.f = f;
  unsigned int r = v.u + 0x7fffu + ((v.u >> 16) & 1u);
  return (unsigned short)(r >> 16);
}

// async 16B global->LDS. LDS dest is wave-uniform base + lane*16 (HW semantics).
__device__ __forceinline__ void gload_lds16(const unsigned short* g, unsigned short* l) {
  __builtin_amdgcn_global_load_lds(
      (const __attribute__((address_space(1))) void*)g,
      (__attribute__((address_space(3))) void*)l, 16, 0, 0);
}

__device__ __forceinline__ void wait_vm0_barrier() {
  asm volatile("s_waitcnt vmcnt(0)" ::: "memory");
  __builtin_amdgcn_s_barrier();
}

template <int N>
__device__ __forceinline__ void wait_vmcnt() {
  if constexpr (N == 0) asm volatile("s_waitcnt vmcnt(0)" ::: "memory");
  else if constexpr (N == 1) asm volatile("s_waitcnt vmcnt(1)" ::: "memory");
  else if constexpr (N == 2) asm volatile("s_waitcnt vmcnt(2)" ::: "memory");
  else if constexpr (N == 3) asm volatile("s_waitcnt vmcnt(3)" ::: "memory");
  else if constexpr (N == 4) asm volatile("s_waitcnt vmcnt(4)" ::: "memory");
  else if constexpr (N == 6) asm volatile("s_waitcnt vmcnt(6)" ::: "memory");
  else if constexpr (N == 8) asm volatile("s_waitcnt vmcnt(8)" ::: "memory");
}

__device__ __forceinline__ void open_phase_barrier() {
  __builtin_amdgcn_s_barrier();
  __builtin_amdgcn_sched_barrier(0);  // keep ds_reads below the barrier (rule #18)
}

// ---------------- transpose fp32 [K][N] -> bf16 [N][K] ----------------
__global__ __launch_bounds__(256) void k_transpose_bf16(
    const float* __restrict__ in, unsigned short* __restrict__ out, int K, int N) {
  __shared__ float t[32][33];
  int tx = threadIdx.x & 31, ty = threadIdx.x >> 5;
  int n0 = blockIdx.x * 32, k0 = blockIdx.y * 32;
#pragma unroll
  for (int i = 0; i < 32; i += 8)
    t[ty + i][tx] = in[(size_t)(k0 + ty + i) * N + n0 + tx];
  __syncthreads();
#pragma unroll
  for (int i = 0; i < 32; i += 8)
    out[(size_t)(n0 + ty + i) * K + k0 + tx] = f2bf(t[tx][ty + i]);
}

// ---------------- V transpose: qkv V-part -> Vt[bh][64][2048] bf16 ----------------
__global__ __launch_bounds__(256) void k_transpose_v(
    const unsigned short* __restrict__ qkv, unsigned short* __restrict__ Vt) {
  __shared__ unsigned short t[32][33];
  int tx = threadIdx.x & 31, ty = threadIdx.x >> 5;  // 32 x 8
  int t0 = blockIdx.x * 32;
  int d0 = (blockIdx.y & 1) * 32;
  int bh = blockIdx.y >> 1;
  int b = bh >> 4, h = bh & 15;
  const unsigned short* src = qkv + (size_t)b * SEQ * THREE_EMBED + 2 * EMBED + h * HDIM;
#pragma unroll
  for (int i = 0; i < 32; i += 8)
    t[ty + i][tx] = src[(size_t)(t0 + ty + i) * THREE_EMBED + d0 + tx];
  __syncthreads();
  unsigned short* dst = Vt + (size_t)bh * HDIM * SEQ;
#pragma unroll
  for (int i = 0; i < 32; i += 8)
    dst[(size_t)(d0 + ty + i) * SEQ + t0 + tx] = t[tx][ty + i];
}

// ---------------- layernorm fp32 [4096][1024] -> bf16 ----------------
__global__ __launch_bounds__(256) void k_layernorm(
    const float* __restrict__ x, const float* __restrict__ g,
    const float* __restrict__ b, unsigned short* __restrict__ out) {
  int row = blockIdx.x;
  int tid = threadIdx.x;
  const float4 xv = *(const float4*)(x + (size_t)row * EMBED + tid * 4);
  float s = xv.x + xv.y + xv.z + xv.w;
  float sq = xv.x * xv.x + xv.y * xv.y + xv.z * xv.z + xv.w * xv.w;
#pragma unroll
  for (int off = 1; off < 64; off <<= 1) {
    s += __shfl_xor(s, off);
    sq += __shfl_xor(sq, off);
  }
  __shared__ float red[8];
  int w = tid >> 6;
  if ((tid & 63) == 0) { red[w] = s; red[4 + w] = sq; }
  __syncthreads();
  s = red[0] + red[1] + red[2] + red[3];
  sq = red[4] + red[5] + red[6] + red[7];
  float mu = s * (1.0f / EMBED);
  float var = sq * (1.0f / EMBED) - mu * mu;
  float rs = rsqrtf(var + 1e-5f);
  float xs[4] = {xv.x, xv.y, xv.z, xv.w};
  unsigned short o[4];
#pragma unroll
  for (int c = 0; c < 4; c++) {
    int col = tid * 4 + c;
    o[c] = f2bf((xs[c] - mu) * rs * g[col] + b[col]);
  }
  *(ushort4*)(out + (size_t)row * EMBED + tid * 4) = *(const ushort4*)o;
}

// ======== 256x256 8-wave 4-phase GEMM v2 (register-held operands) ========
// See R10 notes: 24 b128 LDS reads per K-tile(64) per wave, uniform vmcnt(4),
// one barrier per phase + sched_barrier(0), tail peeled vmcnt 2->0.
template <int EPI>
__global__ __launch_bounds__(512, 2) void k_gemm8(
    const unsigned short* __restrict__ A, const unsigned short* __restrict__ Bt,
    const float* __restrict__ bias, const float* __restrict__ resid,
    float* __restrict__ outf, unsigned short* __restrict__ outb,
    int M, int N, int K) {
  __shared__ unsigned short lA[2][16384];
  __shared__ unsigned short lB[2][16384];
  int tid = threadIdx.x;
  int nwg = gridDim.x * gridDim.y;
  int bid = blockIdx.y * gridDim.x + blockIdx.x;
  int swz = (bid & 7) * (nwg >> 3) + (bid >> 3);
  int m0 = (swz / gridDim.x) * 256, n0 = (swz % gridDim.x) * 256;
  int lane = tid & 63, w = tid >> 6;
  int lr = lane & 15, lg = lane >> 4;
  int warow = (w >> 2) * 64;  // A row base within a half
  int wbrow = (w & 3) * 32;   // B row base within a half
  int rx = lr & 7;
  int colk[2] = {(lg ^ rx) * 8, ((4 + lg) ^ rx) * 8};
  f32x4 acc[8][4] = {};
  int swzk = ((lane & 7) ^ ((lane >> 3) & 7)) * 8;  // pre-swizzled global col (shorts)
  const unsigned short* gA[2];
  const unsigned short* gB[2];
#pragma unroll
  for (int i = 0; i < 2; i++) {
    int chrow = (w * 2 + i) * 8 + (lane >> 3);
    gA[i] = A + (size_t)(m0 + chrow) * K + swzk;
    gB[i] = Bt + (size_t)(n0 + chrow) * K + swzk;
  }
  int NT = K >> 6;
  auto stageA = [&](int h, int kt, int buf) {
    size_t goff = (size_t)(h * 128) * K + (size_t)kt * 64;
    int lo = h * 8192 + w * 1024;
    gload_lds16(gA[0] + goff, &lA[buf][lo]);
    gload_lds16(gA[1] + goff, &lA[buf][lo + 512]);
  };
  auto stageB = [&](int h, int kt, int buf) {
    size_t goff = (size_t)(h * 128) * K + (size_t)kt * 64;
    int lo = h * 8192 + w * 1024;
    gload_lds16(gB[0] + goff, &lB[buf][lo]);
    gload_lds16(gB[1] + goff, &lB[buf][lo + 512]);
  };
  bf16x8 aX[4][2], aY[4][2], b0[2][2], b1[2][2];
  auto rdA = [&](int buf, int mh, bf16x8 (&dst)[4][2]) {
#pragma unroll
    for (int ii = 0; ii < 4; ii++) {
      int ra = mh * 128 + warow + ii * 16 + lr;
#pragma unroll
      for (int ks = 0; ks < 2; ks++)
        dst[ii][ks] = *(const bf16x8*)&lA[buf][ra * 64 + colk[ks]];
    }
  };
  auto rdB = [&](int buf, int nh, bf16x8 (&dst)[2][2]) {
#pragma unroll
    for (int jj = 0; jj < 2; jj++) {
      int rb = nh * 128 + wbrow + jj * 16 + lr;
#pragma unroll
      for (int ks = 0; ks < 2; ks++)
        dst[jj][ks] = *(const bf16x8*)&lB[buf][rb * 64 + colk[ks]];
    }
  };
  auto mf = [&](int mh, int nh, bf16x8 (&aa)[4][2], bf16x8 (&bb)[2][2]) {
    __builtin_amdgcn_s_setprio(1);
#pragma unroll
    for (int ii = 0; ii < 4; ii++)
#pragma unroll
      for (int jj = 0; jj < 2; jj++)
#pragma unroll
        for (int ks = 0; ks < 2; ks++)
          acc[mh * 4 + ii][nh * 2 + jj] =
              MFMA16(aa[ii][ks], bb[jj][ks], acc[mh * 4 + ii][nh * 2 + jj]);
    __builtin_amdgcn_s_setprio(0);
  };
  // prologue: stage tile 0 (A0,B0,B1,A1), drain A0, read its frags
  stageA(0, 0, 0); stageB(0, 0, 0); stageB(1, 0, 0); stageA(1, 0, 0);
  wait_vmcnt<6>();
  open_phase_barrier();
  rdA(0, 0, aX);
  for (int t = 0; t < NT - 1; t++) {
    int cur = t & 1, nxt = cur ^ 1;
    stageA(0, t + 1, nxt);
    wait_vmcnt<4>();
    open_phase_barrier();
    rdB(cur, 0, b0);
    rdB(cur, 1, b1);
    mf(0, 0, aX, b0);
    stageB(0, t + 1, nxt);
    wait_vmcnt<4>();
    open_phase_barrier();
    rdA(cur, 1, aY);
    mf(0, 1, aX, b1);
    stageB(1, t + 1, nxt);
    wait_vmcnt<4>();
    open_phase_barrier();
    mf(1, 1, aY, b1);
    stageA(1, t + 1, nxt);
    wait_vmcnt<4>();
    open_phase_barrier();
    rdA(nxt, 0, aX);
    mf(1, 0, aY, b0);
  }
  {  // tail tile NT-1 (no staging), tightening drains
    int cur = (NT - 1) & 1;
    wait_vmcnt<2>();
    open_phase_barrier();
    rdB(cur, 0, b0);
    rdB(cur, 1, b1);
    mf(0, 0, aX, b0);
    wait_vmcnt<0>();
    open_phase_barrier();
    rdA(cur, 1, aY);
    mf(0, 1, aX, b1);
    mf(1, 1, aY, b1);
    mf(1, 0, aY, b0);
  }
  // epilogue (split-half output mapping)
#pragma unroll
  for (int i = 0; i < 8; i++) {
#pragma unroll
    for (int j = 0; j < 4; j++) {
      int col = n0 + (j >> 1) * 128 + wbrow + (j & 1) * 16 + lr;
      float bv = bias[col];
#pragma unroll
      for (int r = 0; r < 4; r++) {
        int row = m0 + (i >> 2) * 128 + warow + (i & 3) * 16 + lg * 4 + r;
        float v = acc[i][j][r] + bv;
        size_t idx = (size_t)row * N + col;
        if constexpr (EPI == 0) {
          outb[idx] = f2bf(v);
        } else if constexpr (EPI == 1) {
          outf[idx] = v + resid[idx];
        } else {
          float gv = 0.5f * v * (1.0f + erff(v * 0.70710678118654752f));
          outb[idx] = f2bf(gv);
        }
      }
    }
  }
}

// ---- narrow GEMM (BM=128, BN=64, BK=64): 3-buffer counted-vmcnt pipeline ----
// 4 waves, wave tile 32x64: per K-step 16 MFMA + 12 ds_read_b128 + 6 gload/wave,
// HALF the barriers of BK=32. Chunks of 1KB (8 rows x 64 cols): A=16, B=8, 6/wave.
// T2 swizzle for 128B rows: stored slot = slot ^ (row&7) via pre-swizzled global
// source; fragment col = ((ks*4+lg) ^ (lr&7))*8 (constant per thread).
// Queue math: prefetch 2 tiles ahead, wait vmcnt(6) => t+1's 6 loads landed,
// t+2's 6 in flight across the barrier. Tail peeled vmcnt(0).
template <int EPI>
__global__ __launch_bounds__(256) void k_gemmN(
    const unsigned short* __restrict__ A, const unsigned short* __restrict__ Bt,
    const float* __restrict__ bias, const float* __restrict__ resid,
    float* __restrict__ outf, unsigned short* __restrict__ outb,
    int M, int N, int K) {
  __shared__ unsigned short lA[3][128 * 64];
  __shared__ unsigned short lB[3][64 * 64];
  int tid = threadIdx.x;
  int nwg = gridDim.x * gridDim.y;
  int bid = blockIdx.y * gridDim.x + blockIdx.x;
  int swz = (bid & 7) * (nwg >> 3) + (bid >> 3);
  int m0 = (swz / gridDim.x) * 128, n0 = (swz % gridDim.x) * 64;
  int lane = tid & 63, w = tid >> 6;
  int wm = w * 32;
  int lr = lane & 15, lg = lane >> 4;
  int rx = lr & 7;
  int colk[2] = {(lg ^ rx) * 8, ((4 + lg) ^ rx) * 8};
  f32x4 acc[2][4] = {};
  // staging: 24 chunks (A:0-15, B:16-23), wave w owns [w*6, w*6+6)
  int swzk = ((lane & 7) ^ ((lane >> 3) & 7)) * 8;  // pre-swizzled global col (shorts)
  const unsigned short* gsrc[6];
  int loff[6];
  bool isa[6];
#pragma unroll
  for (int c0 = 0; c0 < 6; c0++) {
    int c = w * 6 + c0;
    if (c < 16) {
      int row = c * 8 + (lane >> 3);
      gsrc[c0] = A + (size_t)(m0 + row) * K + swzk;
      loff[c0] = c * 512;
      isa[c0] = true;
    } else {
      int row = (c - 16) * 8 + (lane >> 3);
      gsrc[c0] = Bt + (size_t)(n0 + row) * K + swzk;
      loff[c0] = (c - 16) * 512;
      isa[c0] = false;
    }
  }
  auto stage = [&](int k0, int buf) {
#pragma unroll
    for (int c0 = 0; c0 < 6; c0++)
      gload_lds16(gsrc[c0] + k0, isa[c0] ? &lA[buf][loff[c0]] : &lB[buf][loff[c0]]);
  };
  auto compute = [&](int buf) {
    bf16x8 af[2][2], bf[4][2];
#pragma unroll
    for (int i = 0; i < 2; i++)
#pragma unroll
      for (int ks = 0; ks < 2; ks++)
        af[i][ks] = *(const bf16x8*)&lA[buf][(wm + i * 16 + lr) * 64 + colk[ks]];
#pragma unroll
    for (int j = 0; j < 4; j++)
#pragma unroll
      for (int ks = 0; ks < 2; ks++)
        bf[j][ks] = *(const bf16x8*)&lB[buf][(j * 16 + lr) * 64 + colk[ks]];
    __builtin_amdgcn_s_setprio(1);
#pragma unroll
    for (int i = 0; i < 2; i++)
#pragma unroll
      for (int j = 0; j < 4; j++)
#pragma unroll
        for (int ks = 0; ks < 2; ks++)
          acc[i][j] = MFMA16(af[i][ks], bf[j][ks], acc[i][j]);
    __builtin_amdgcn_s_setprio(0);
  };
  int nt = K >> 6;  // >= 16 for our shapes
  stage(0, 0);
  stage(64, 1);
  wait_vmcnt<6>();  // tile 0 landed; tile 1's 6 loads may be in flight
  __builtin_amdgcn_s_barrier();
  int c0 = 0, c1 = 1, c2 = 2;
  for (int t = 0; t < nt - 2; t++) {
    stage((t + 2) * 64, c2);
    compute(c0);
    wait_vmcnt<6>();  // t+1's loads done; t+2's stay in flight
    __builtin_amdgcn_s_barrier();
    int tmp = c0; c0 = c1; c1 = c2; c2 = tmp;
  }
  compute(c0);
  wait_vmcnt<0>();
  __builtin_amdgcn_s_barrier();
  compute(c1);
#pragma unroll
  for (int i = 0; i < 2; i++) {
#pragma unroll
    for (int j = 0; j < 4; j++) {
      int colb = n0 + j * 16 + lr;
      float bv = bias[colb];
#pragma unroll
      for (int r = 0; r < 4; r++) {
        int row = m0 + wm + i * 16 + lg * 4 + r;
        float v = acc[i][j][r] + bv;
        size_t idx = (size_t)row * N + colb;
        if constexpr (EPI == 0) {
          outb[idx] = f2bf(v);
        } else if constexpr (EPI == 1) {
          outf[idx] = v + resid[idx];
        } else {
          float gv = 0.5f * v * (1.0f + erff(v * 0.70710678118654752f));
          outb[idx] = f2bf(gv);
        }
      }
    }
  }
}

// ---------------- causal flash attention ----------------
__global__ __launch_bounds__(256) void k_attention(
    const unsigned short* __restrict__ qkv, const unsigned short* __restrict__ Vt,
    unsigned short* __restrict__ out) {
  __shared__ unsigned short lK[2][64 * 64];
  __shared__ unsigned short lV[2][64 * 64];
  __shared__ unsigned short lP[4][16][72];
  int bid = blockIdx.x;
  int i = bid >> 3;
  int qt = 31 - (i >> 2);
  int bh = (bid & 7) * 4 + (i & 3);
  int b = bh >> 4, h = bh & 15;
  int tid = threadIdx.x, lane = tid & 63, w = tid >> 6;
  int lr = lane & 15, lg = lane >> 4;
  const unsigned short* base = qkv + (size_t)b * SEQ * THREE_EMBED + h * HDIM;
  const unsigned short* Kb = base + EMBED;
  const unsigned short* Vb = Vt + (size_t)bh * HDIM * SEQ;
  int q0 = qt * 64 + w * 16;
  bf16x8 qf[2];
  {
    int qrow = q0 + lr;
    qf[0] = *(const bf16x8*)(base + (size_t)qrow * THREE_EMBED + lg * 8);
    qf[1] = *(const bf16x8*)(base + (size_t)qrow * THREE_EMBED + 32 + lg * 8);
  }
  bf16x8 ones;
  {
    short o1 = 0x3F80;
#pragma unroll
    for (int j = 0; j < 8; j++) ones[j] = o1;
  }
  f32x4 o[4] = {};
  f32x4 osum = {};
  float m_[4] = {-INFINITY, -INFINITY, -INFINITY, -INFINITY};
  int srow = lane >> 3;
  int scol = ((lane & 7) ^ (lane >> 3)) * 8;
  const float SCL = 0.125f * 1.4426950408889634f;
  int nkv = qt + 1;
  auto stage = [&](int kt, int cur) {
#pragma unroll
    for (int c = 0; c < 2; c++) {
      int chunk = w * 2 + c;
      int row = chunk * 8 + srow;
      gload_lds16(Kb + (size_t)(kt * 64 + row) * THREE_EMBED + scol, &lK[cur][chunk * 512]);
      gload_lds16(Vb + (size_t)row * SEQ + kt * 64 + scol, &lV[cur][chunk * 512]);
    }
  };
  stage(0, 0);
  wait_vm0_barrier();
  int cur = 0;
  for (int kt = 0; kt < nkv; kt++) {
    if (kt + 1 < nkv) stage(kt + 1, cur ^ 1);
    __builtin_amdgcn_s_setprio(1);
    f32x4 s[4];
#pragma unroll
    for (int ct = 0; ct < 4; ct++) {
      int krow = ct * 16 + lr;
      int sw = (krow & 7) << 3;
      bf16x8 k0 = *(const bf16x8*)&lK[cur][krow * 64 + ((lg * 8) ^ sw)];
      bf16x8 k1 = *(const bf16x8*)&lK[cur][krow * 64 + ((32 + lg * 8) ^ sw)];
      f32x4 z = {};
      z = MFMA16(qf[0], k0, z);
      s[ct] = MFMA16(qf[1], k1, z);
    }
    __builtin_amdgcn_s_setprio(0);
    bool maskt = (kt * 64 + 63 > q0);
    float pm[4] = {-INFINITY, -INFINITY, -INFINITY, -INFINITY};
#pragma unroll
    for (int ct = 0; ct < 4; ct++) {
#pragma unroll
      for (int r = 0; r < 4; r++) {
        float sv = s[ct][r] * SCL;
        if (maskt) {
          int kg = kt * 64 + ct * 16 + lr;
          int qg = q0 + lg * 4 + r;
          if (kg > qg) sv = -INFINITY;
        }
        s[ct][r] = sv;
        pm[r] = fmaxf(pm[r], sv);
      }
    }
    float dm = fmaxf(fmaxf(pm[0] - m_[0], pm[1] - m_[1]),
                     fmaxf(pm[2] - m_[2], pm[3] - m_[3]));
    if (!__all(dm <= 8.0f)) {
#pragma unroll
      for (int r = 0; r < 4; r++) {
        float mx = pm[r];
        mx = fmaxf(mx, __shfl_xor(mx, 1));
        mx = fmaxf(mx, __shfl_xor(mx, 2));
        mx = fmaxf(mx, __shfl_xor(mx, 4));
        mx = fmaxf(mx, __shfl_xor(mx, 8));
        float mn = fmaxf(m_[r], mx);
        float al = exp2f(m_[r] - mn);
        m_[r] = mn;
        osum[r] *= al;
#pragma unroll
        for (int dt = 0; dt < 4; dt++) o[dt][r] *= al;
      }
    }
#pragma unroll
    for (int ct = 0; ct < 4; ct++)
#pragma unroll
      for (int r = 0; r < 4; r++)
        lP[w][lg * 4 + r][ct * 16 + lr] = f2bf(exp2f(s[ct][r] - m_[r]));
    __builtin_amdgcn_s_setprio(1);
#pragma unroll
    for (int ks = 0; ks < 2; ks++) {
      bf16x8 pf = *(const bf16x8*)&lP[w][lr][ks * 32 + lg * 8];
      osum = MFMA16(pf, ones, osum);
#pragma unroll
      for (int dt = 0; dt < 4; dt++) {
        int vrow = dt * 16 + lr;
        int sw = (vrow & 7) << 3;
        bf16x8 vf = *(const bf16x8*)&lV[cur][vrow * 64 + ((ks * 32 + lg * 8) ^ sw)];
        o[dt] = MFMA16(pf, vf, o[dt]);
      }
    }
    __builtin_amdgcn_s_setprio(0);
    wait_vm0_barrier();
    cur ^= 1;
  }
#pragma unroll
  for (int dt = 0; dt < 4; dt++)
#pragma unroll
    for (int r = 0; r < 4; r++) {
      int row = q0 + lg * 4 + r;
      float val = o[dt][r] / osum[r];
      out[(size_t)(b * SEQ + row) * EMBED + h * HDIM + dt * 16 + lr] = f2bf(val);
    }
}

extern "C" void kernel_launch(void* const* d_in, const int* in_sizes, int n_in,
                              void* d_out, int out_size, void* d_ws, size_t ws_size,
                              hipStream_t stream) {
  const float* x      = (const float*)d_in[0];
  const float* ln1_g  = (const float*)d_in[1];
  const float* ln1_b  = (const float*)d_in[2];
  const float* w_attn = (const float*)d_in[3];
  const float* b_attn = (const float*)d_in[4];
  const float* w_proj = (const float*)d_in[5];
  const float* b_proj = (const float*)d_in[6];
  const float* ln2_g  = (const float*)d_in[7];
  const float* ln2_b  = (const float*)d_in[8];
  const float* w_fc   = (const float*)d_in[9];
  const float* b_fc   = (const float*)d_in[10];
  const float* w_fc2  = (const float*)d_in[11];
  const float* b_fc2  = (const float*)d_in[12];
  float* outp = (float*)d_out;

  char* ws = (char*)d_ws;
  unsigned short* wT_attn = (unsigned short*)(ws);             // [3072][1024] bf16, 6 MB
  unsigned short* wT_proj = (unsigned short*)(ws + 6291456);   // [1024][1024] bf16, 2 MB
  unsigned short* wT_fc   = (unsigned short*)(ws + 8388608);   // [4096][1024] bf16, 8 MB
  unsigned short* wT_fc2  = (unsigned short*)(ws + 16777216);  // [1024][4096] bf16, 8 MB
  unsigned short* buf1    = (unsigned short*)(ws + 25165824);  // 8 MB: xln -> attnout -> x2ln
  float*          x1      = (float*)(ws + 33554432);           // 16 MB fp32 (written after attention)
  unsigned short* Vt      = (unsigned short*)(ws + 33554432);  // 8 MB bf16, dead once attention done
  unsigned short* qkv_h   = (unsigned short*)(ws + 50331648);  // 24 MB qkv -> 32 MB h (48..80 MB)

  dim3 blk(256);
  k_transpose_bf16<<<dim3(3072 / 32, 1024 / 32), blk, 0, stream>>>(w_attn, wT_attn, 1024, 3072);
  k_transpose_bf16<<<dim3(1024 / 32, 1024 / 32), blk, 0, stream>>>(w_proj, wT_proj, 1024, 1024);
  k_transpose_bf16<<<dim3(4096 / 32, 1024 / 32), blk, 0, stream>>>(w_fc, wT_fc, 1024, 4096);
  k_transpose_bf16<<<dim3(1024 / 32, 4096 / 32), blk, 0, stream>>>(w_fc2, wT_fc2, 4096, 1024);
  // LN1: x -> xln (buf1)
  k_layernorm<<<dim3(MTOT), blk, 0, stream>>>(x, ln1_g, ln1_b, buf1);
  // QKV: 256^2 v2, 12x16 = 192 blocks
  k_gemm8<0><<<dim3(THREE_EMBED / 256, MTOT / 256), dim3(512), 0, stream>>>(
      buf1, wT_attn, b_attn, nullptr, nullptr, qkv_h, MTOT, THREE_EMBED, EMBED);
  // V transpose for attention
  k_transpose_v<<<dim3(SEQ / 32, 2 * BATCH * HEADS), blk, 0, stream>>>(qkv_h, Vt);
  // attention -> attnout (buf1)
  k_attention<<<dim3(1024), blk, 0, stream>>>(qkv_h, Vt, buf1);
  // proj + residual: narrow BK=64, 16x32 = 512 blocks (overwrites Vt — dead)
  k_gemmN<1><<<dim3(EMBED / 64, MTOT / 128), blk, 0, stream>>>(
      buf1, wT_proj, b_proj, x, x1, nullptr, MTOT, EMBED, EMBED);
  // LN2: x1 -> x2ln (buf1)
  k_layernorm<<<dim3(MTOT), blk, 0, stream>>>(x1, ln2_g, ln2_b, buf1);
  // FC1 + GELU: 256^2 v2, 16x16 = 256 blocks
  k_gemm8<2><<<dim3(4 * EMBED / 256, MTOT / 256), dim3(512), 0, stream>>>(
      buf1, wT_fc, b_fc, nullptr, nullptr, qkv_h, MTOT, 4 * EMBED, EMBED);
  // FC2 + residual -> out: narrow BK=64, 512 blocks
  k_gemmN<1><<<dim3(EMBED / 64, MTOT / 128), blk, 0, stream>>>(
      qkv_h, wT_fc2, b_fc2, x1, outp, nullptr, MTOT, EMBED, 4 * EMBED);
}